// Round 12
// baseline (1314.026 us; speedup 1.0000x reference)
//
#include <hip/hip_runtime.h>

#pragma clang fp contract(off)

typedef unsigned long long u64;
typedef unsigned int u32;

#define ALPHA  0.9f
#define RHO    0.985f
#define BETA_A 1.8f
#define TH     1.0f
#define CAP    (1 << 24)

// ---------------------------------------------------------------------------
// Generic 32x32 tiled transpose: src[R][C] -> dst[C][R]
// ---------------------------------------------------------------------------
__global__ __launch_bounds__(256) void transpose_k(const float* __restrict__ src,
                                                   float* __restrict__ dst,
                                                   int R, int C) {
    __shared__ float tile[32][33];
    const int c0 = blockIdx.x * 32;
    const int r0 = blockIdx.y * 32;
    const int tx = threadIdx.x, ty = threadIdx.y;
#pragma unroll
    for (int i = 0; i < 4; ++i)
        tile[ty + i * 8][tx] = src[(r0 + ty + i * 8) * C + c0 + tx];
    __syncthreads();
#pragma unroll
    for (int i = 0; i < 4; ++i)
        dst[(c0 + ty + i * 8) * R + r0 + tx] = tile[tx][ty + i * 8];
}

// ---------------------------------------------------------------------------
// Merged input projection: both IP_pre and IP_post from one s_in staging
// (validated rounds 10-11).
// ---------------------------------------------------------------------------
__global__ __launch_bounds__(256) void ip_gemm2(const float* __restrict__ inp,
                                                const float* __restrict__ Wt_a,
                                                const float* __restrict__ bias_a,
                                                float* __restrict__ out_a,
                                                const float* __restrict__ Wt_b,
                                                const float* __restrict__ bias_b,
                                                float* __restrict__ out_b) {
    __shared__ __align__(16) float s_in[512 * 20];
    const int tid   = threadIdx.x;
    const int chunk = blockIdx.x;
    const int rbase = blockIdx.y * 16;

    for (int idx = tid; idx < 16 * 512; idx += 256) {
        const int r = idx >> 9, k = idx & 511;
        s_in[k * 20 + r] = inp[(rbase + r) * 512 + k];
    }
    __syncthreads();

    const int n = chunk * 256 + tid;
    float acca[16], accb[16];
#pragma unroll
    for (int r = 0; r < 16; ++r) { acca[r] = 0.f; accb[r] = 0.f; }

    for (int k = 0; k < 512; ++k) {
        const float wa = Wt_a[k * 1024 + n];
        const float wb = Wt_b[k * 1024 + n];
        const float4* p = (const float4*)(s_in + k * 20);
        const float4 x0 = p[0], x1 = p[1], x2 = p[2], x3 = p[3];
        acca[0]  = fmaf(x0.x, wa, acca[0]);  accb[0]  = fmaf(x0.x, wb, accb[0]);
        acca[1]  = fmaf(x0.y, wa, acca[1]);  accb[1]  = fmaf(x0.y, wb, accb[1]);
        acca[2]  = fmaf(x0.z, wa, acca[2]);  accb[2]  = fmaf(x0.z, wb, accb[2]);
        acca[3]  = fmaf(x0.w, wa, acca[3]);  accb[3]  = fmaf(x0.w, wb, accb[3]);
        acca[4]  = fmaf(x1.x, wa, acca[4]);  accb[4]  = fmaf(x1.x, wb, accb[4]);
        acca[5]  = fmaf(x1.y, wa, acca[5]);  accb[5]  = fmaf(x1.y, wb, accb[5]);
        acca[6]  = fmaf(x1.z, wa, acca[6]);  accb[6]  = fmaf(x1.z, wb, accb[6]);
        acca[7]  = fmaf(x1.w, wa, acca[7]);  accb[7]  = fmaf(x1.w, wb, accb[7]);
        acca[8]  = fmaf(x2.x, wa, acca[8]);  accb[8]  = fmaf(x2.x, wb, accb[8]);
        acca[9]  = fmaf(x2.y, wa, acca[9]);  accb[9]  = fmaf(x2.y, wb, accb[9]);
        acca[10] = fmaf(x2.z, wa, acca[10]); accb[10] = fmaf(x2.z, wb, accb[10]);
        acca[11] = fmaf(x2.w, wa, acca[11]); accb[11] = fmaf(x2.w, wb, accb[11]);
        acca[12] = fmaf(x3.x, wa, acca[12]); accb[12] = fmaf(x3.x, wb, accb[12]);
        acca[13] = fmaf(x3.y, wa, acca[13]); accb[13] = fmaf(x3.y, wb, accb[13]);
        acca[14] = fmaf(x3.z, wa, acca[14]); accb[14] = fmaf(x3.z, wb, accb[14]);
        acca[15] = fmaf(x3.w, wa, acca[15]); accb[15] = fmaf(x3.w, wb, accb[15]);
    }
    const float bna = bias_a[n];
    const float bnb = bias_b[n];
#pragma unroll
    for (int r = 0; r < 16; ++r) {
        out_a[(rbase + r) * 1024 + n] = acca[r] + bna;
        out_b[(rbase + r) * 1024 + n] = accb[r] + bnb;
    }
}

// ---------------------------------------------------------------------------
__device__ __forceinline__ u64 ld_u64(const u64* p) {
    return __hip_atomic_load(p, __ATOMIC_RELAXED, __HIP_MEMORY_SCOPE_AGENT);
}
__device__ __forceinline__ void st_u64(u64* p, u64 v) {
    __hip_atomic_store(p, v, __ATOMIC_RELAXED, __HIP_MEMORY_SCOPE_AGENT);
}

// Gather over byte-offset list segment [i0, i1), i0 % 4 == 0.
// 8 independent accumulator chains (two int4 reads per iter) -> 8 outstanding
// weight loads per wave, doubling memory-level parallelism vs round 7's 4.
__device__ __forceinline__ float gatherseg(const char* __restrict__ Wb,
                                           const int* __restrict__ list,
                                           int i0, int i1, int colB) {
    float a0 = 0.f, a1 = 0.f, a2 = 0.f, a3 = 0.f;
    float a4 = 0.f, a5 = 0.f, a6 = 0.f, a7 = 0.f;
    int i = i0;
    for (; i + 8 <= i1; i += 8) {
        const int4 j0 = *(const int4*)(list + i);
        const int4 j1 = *(const int4*)(list + i + 4);
        a0 += *(const float*)(Wb + (u32)(j0.x + colB));
        a1 += *(const float*)(Wb + (u32)(j0.y + colB));
        a2 += *(const float*)(Wb + (u32)(j0.z + colB));
        a3 += *(const float*)(Wb + (u32)(j0.w + colB));
        a4 += *(const float*)(Wb + (u32)(j1.x + colB));
        a5 += *(const float*)(Wb + (u32)(j1.y + colB));
        a6 += *(const float*)(Wb + (u32)(j1.z + colB));
        a7 += *(const float*)(Wb + (u32)(j1.w + colB));
    }
    for (; i + 4 <= i1; i += 4) {
        const int4 j = *(const int4*)(list + i);
        a0 += *(const float*)(Wb + (u32)(j.x + colB));
        a1 += *(const float*)(Wb + (u32)(j.y + colB));
        a2 += *(const float*)(Wb + (u32)(j.z + colB));
        a3 += *(const float*)(Wb + (u32)(j.w + colB));
    }
    for (; i < i1; ++i) a0 += *(const float*)(Wb + (u32)(list[i] + colB));
    return ((a0 + a1) + (a2 + a3)) + ((a4 + a5) + (a6 + a7));
}

// index-based gather for out_gemm
__device__ __forceinline__ float gather_idx(const float* __restrict__ W,
                                            const int* __restrict__ list, int cnt, int col) {
    float a0 = 0.f, a1 = 0.f, a2 = 0.f, a3 = 0.f;
    int i = 0;
    for (; i + 4 <= cnt; i += 4) {
        const int4 j = *(const int4*)(list + i);
        a0 += W[j.x * 256 + col];
        a1 += W[j.y * 256 + col];
        a2 += W[j.z * 256 + col];
        a3 += W[j.w * 256 + col];
    }
    for (; i < cnt; ++i) a0 += W[list[i] * 256 + col];
    return (a0 + a1) + (a2 + a3);
}

// ---------------------------------------------------------------------------
// Producer-consumer main kernel (round 7's validated 890 us engine, only the
// gather ILP upgraded): 256 blocks x 640 threads.
// Waves 0-7 compute (slice s = (bid&7)>>1: cols [s*256,s*256+256), pair
// p = (bid>>3)*2+(bid&1): batches 2p,2p+1). Wave 8 polls exchange-1 (s_pre)
// and builds listP; wave 9 polls exchange-2 (s_a) and builds listS[par].
// Publish: each compute wave's lane0 stores 2 epoch-tagged words
// ((e<<32)|bits32) immediately after its ballot -- no barrier before publish.
// 2 barriers per phase (B1 releases listP, B2 releases listS).
// FILL-2 at epoch e finishes v_post of phase ph=e-1; s_post emitted when
// k(ph)=(ph-1)%3==2  <=>  e%3==1.
// ---------------------------------------------------------------------------
__global__ __launch_bounds__(640) void rsnn_pc(
    const float* __restrict__ Wt_pre,   // [1536][1024]
    const float* __restrict__ Wt_ad,    // [1024][1024]
    const float* __restrict__ Wt_post,  // [1536][1024]
    const float* __restrict__ IP_pre,   // [4096][1024]
    const float* __restrict__ IP_post,  // [4096][1024]
    const float* __restrict__ b_ad_p,   // [1024]
    u64* __restrict__ lines,            // [64 pairs][2 par][2 ty][64]
    u64* __restrict__ spkO,             // [4096][16]
    float* __restrict__ out)
{
    const int tid  = threadIdx.x;
    const int bid  = blockIdx.x;
    const int x    = bid & 7;
    const int g    = bid >> 3;
    const int s    = x >> 1;
    const int p    = g * 2 + (x & 1);
    const int wid  = tid >> 6;
    const int lane = tid & 63;

    __shared__ __align__(16) int listP[2][1024];      // [bi]
    __shared__ __align__(16) int listS[2][2][1024];   // [par][bi]
    __shared__ int cntP_ls[2], cntS_ls[2][2];

    const char* WadB    = (const char*)Wt_ad;
    const char* WpreAB  = (const char*)(Wt_pre  + 512 * 1024);
    const char* WpostAB = (const char*)(Wt_post + 512 * 1024);

    if (wid < 8) {
        // ============================ compute ============================
        const int bi   = tid >> 8;
        const int c    = tid & 255;
        const int col  = s * 256 + c;
        const int b    = 2 * p + bi;
        const int q    = wid & 3;
        const int colB = col * 4;

        float v_pre = 0.f, v_a = 0.f, ba = 0.f, v_post = 0.f, accA = 0.f;
        bool  sa = false;
        const float bad = b_ad_p[col];
        float g1 = 0.f;
        int halfPrev = 0, cntPrev = 0, parPrev = 0;

        for (int e = 1; e <= 96; ++e) {
            const int par = e & 1;
            const int t   = (e - 1) / 3;
            const float ipre = IP_pre[(t * 128 + b) * 1024 + col];
            u64* ln0 = lines + ((p * 2 + par) * 2 + 0) * 64;
            u64* ln1 = lines + ((p * 2 + par) * 2 + 1) * 64;

            // ---- A: v_pre update, immediate per-wave publish ----
            v_pre = ALPHA * v_pre + ipre + accA;
            float d = v_pre - TH;
            const bool sp = d > 0.f;
            if (sp) v_pre = d;
            {
                const u64 m = __ballot(sp);
                if (lane == 0) {
                    const u64 eh = ((u64)e) << 32;
                    st_u64(&ln0[(s * 2 + bi) * 8 + 2 * q],     eh | (m & 0xffffffffull));
                    st_u64(&ln0[(s * 2 + bi) * 8 + 2 * q + 1], eh | (m >> 32));
                }
            }
            // ---- FILL-1: first half of C(e-1) gather ----
            if (e >= 2)
                g1 = gatherseg(WpostAB, listS[parPrev][bi], 0, halfPrev, colB);
            __syncthreads();                                      // B1

            // ---- B: gather full s_pre list, v_a update, publish s_a ----
            const int cp = cntP_ls[bi];
            const float accB = gatherseg(WadB, listP[bi], 0, cp, colB);
            v_a = ALPHA * v_a + accB + bad;
            const float th = TH + BETA_A * ba;
            d = v_a - th;
            sa = d > 0.f;
            if (sa) v_a = d;
            ba = RHO * ba + (sa ? 1.f : 0.f);
            {
                const u64 m = __ballot(sa);
                if (lane == 0) {
                    const u64 eh = ((u64)e) << 32;
                    st_u64(&ln1[(s * 2 + bi) * 8 + 2 * q],     eh | (m & 0xffffffffull));
                    st_u64(&ln1[(s * 2 + bi) * 8 + 2 * q + 1], eh | (m >> 32));
                }
            }
            // ---- FILL-2: rest of C(e-1), finish v_post(e-1) ----
            if (e >= 2) {
                const float g2 = gatherseg(WpostAB, listS[parPrev][bi],
                                           halfPrev, cntPrev, colB);
                const int tp = (e - 2) / 3;
                const float ipost = IP_post[(tp * 128 + b) * 1024 + col];
                v_post = ALPHA * v_post + ipost + (g1 + g2);
                float dd = v_post - TH;
                const bool spost = dd > 0.f;
                if (spost) v_post = dd;
                if (e % 3 == 1) {   // ph=e-1 has k==2
                    const u64 m = __ballot(spost);
                    if (lane == 0)
                        st_u64(&spkO[(tp * 128 + 2 * p + bi) * 16 + s * 4 + q], m);
                }
            }
            if (e == 96)
                out[32 * 128 * 256 + b * 1024 + col] = sa ? 1.f : 0.f;
            __syncthreads();                                      // B2

            // ---- next-A gather from fresh listS ----
            const int cs = cntS_ls[par][bi];
            halfPrev = (cs >> 1) & ~3;
            cntPrev  = cs;
            parPrev  = par;
            if (e < 96)
                accA = gatherseg(WpreAB, listS[par][bi], 0, cs, colB);
        }
        // ---- epilogue: v_post(96) (par(96) == 0) ----
        {
            const float ga = gatherseg(WpostAB, listS[0][bi], 0, halfPrev, colB);
            const float gb = gatherseg(WpostAB, listS[0][bi], halfPrev, cntPrev, colB);
            const float ipost = IP_post[(31 * 128 + b) * 1024 + col];
            v_post = ALPHA * v_post + ipost + (ga + gb);
            const float dd = v_post - TH;
            const u64 m = __ballot(dd > 0.f);
            if (lane == 0)
                st_u64(&spkO[(31 * 128 + 2 * p + bi) * 16 + s * 4 + q], m);
        }
    } else if (wid == 8) {
        // ================== comm wave: exchange-1 -> listP ==================
        const int cbi = lane >> 5, r = lane & 31, sl = r >> 3, h = r & 7;
        const int jbase = (sl * 256 + h * 32) << 12;
        for (int e = 1; e <= 96; ++e) {
            const int par = e & 1;
            const u64* ln0 = lines + ((p * 2 + par) * 2 + 0) * 64;
            u64 w; int gd = 0;
            do { w = ld_u64(&ln0[(sl * 2 + cbi) * 8 + h]); }
            while ((w >> 32) != (u64)e && ++gd < CAP);
            const u32 bits = (u32)w;
            const int pc = __popc(bits);
            int incl = pc;
            for (int dlt = 1; dlt < 32; dlt <<= 1) {
                const int v = __shfl_up(incl, dlt, 32);
                if ((lane & 31) >= dlt) incl += v;
            }
            int base = incl - pc;
            u32 m = bits;
            while (m) {
                const int bt = __builtin_ctz(m);
                m &= m - 1;
                listP[cbi][base++] = jbase + (bt << 12);
            }
            if ((lane & 31) == 31) cntP_ls[cbi] = incl;
            __syncthreads();                                      // B1
            __syncthreads();                                      // B2
        }
    } else {
        // ================== comm wave: exchange-2 -> listS[par] =============
        const int cbi = lane >> 5, r = lane & 31, sl = r >> 3, h = r & 7;
        const int jbase = (sl * 256 + h * 32) << 12;
        for (int e = 1; e <= 96; ++e) {
            const int par = e & 1;
            const u64* ln1 = lines + ((p * 2 + par) * 2 + 1) * 64;
            __syncthreads();                                      // B1
            u64 w; int gd = 0;
            do { w = ld_u64(&ln1[(sl * 2 + cbi) * 8 + h]); }
            while ((w >> 32) != (u64)e && ++gd < CAP);
            const u32 bits = (u32)w;
            const int pc = __popc(bits);
            int incl = pc;
            for (int dlt = 1; dlt < 32; dlt <<= 1) {
                const int v = __shfl_up(incl, dlt, 32);
                if ((lane & 31) >= dlt) incl += v;
            }
            int base = incl - pc;
            u32 m = bits;
            while (m) {
                const int bt = __builtin_ctz(m);
                m &= m - 1;
                listS[par][cbi][base++] = jbase + (bt << 12);
            }
            if ((lane & 31) == 31) cntS_ls[par][cbi] = incl;
            __syncthreads();                                      // B2
        }
    }
}

// ---------------------------------------------------------------------------
// Final output GEMM: o[r] = s_post[r] @ W_out.T + b_out, from spkO bitmaps.
// ---------------------------------------------------------------------------
__global__ __launch_bounds__(256) void out_gemm(const float* __restrict__ Wt_out,
                                                const float* __restrict__ b_out,
                                                const u64* __restrict__ spkO,
                                                float* __restrict__ out) {
    __shared__ u64 bmp[16];
    __shared__ int pc[16];
    __shared__ __align__(16) int list[1024];
    const int r = blockIdx.x, tid = threadIdx.x;
    if (tid < 16) {
        const u64 m = ld_u64(&spkO[r * 16 + tid]);
        bmp[tid] = m;
        pc[tid]  = __popcll(m);
    }
    __syncthreads();
    int total = 0;
#pragma unroll
    for (int w = 0; w < 16; ++w) total += pc[w];
    for (int j = tid; j < 1024; j += 256) {
        const int w = j >> 6, bit = j & 63;
        const u64 m = bmp[w];
        if ((m >> bit) & 1ull) {
            int base = __popcll(m & ((1ull << bit) - 1ull));
            for (int q2 = 0; q2 < w; ++q2) base += pc[q2];
            list[base] = j;
        }
    }
    __syncthreads();
    const float acc = gather_idx(Wt_out, list, total, tid);
    out[r * 256 + tid] = acc + b_out[tid];
}

// ---------------------------------------------------------------------------
extern "C" void kernel_launch(void* const* d_in, const int* in_sizes, int n_in,
                              void* d_out, int out_size, void* d_ws, size_t ws_size,
                              hipStream_t stream) {
    (void)in_sizes; (void)n_in; (void)out_size; (void)ws_size;
    const float* inp    = (const float*)d_in[0];
    const float* W_pre  = (const float*)d_in[1];
    const float* b_pre  = (const float*)d_in[2];
    const float* W_ad   = (const float*)d_in[3];
    const float* b_ad   = (const float*)d_in[4];
    const float* W_post = (const float*)d_in[5];
    const float* b_post = (const float*)d_in[6];
    const float* W_out  = (const float*)d_in[7];
    const float* b_out  = (const float*)d_in[8];

    char* base = (char*)d_ws;
    u64*  lines = (u64*)(base + 4096);               // 128 KB exchange lines
    u64*  spkO  = (u64*)(base + 147456);             // 512 KB
    float* ws      = (float*)(base + 1048576);
    float* Wt_pre  = ws;
    float* Wt_post = Wt_pre  + 1536 * 1024;
    float* Wt_ad   = Wt_post + 1536 * 1024;
    float* Wt_out  = Wt_ad   + 1024 * 1024;
    float* IP_pre  = Wt_out  + 1024 * 256;
    float* IP_post = IP_pre  + 4096 * 1024;

    hipMemsetAsync(base, 0, 4096 + 131072, stream);  // zero exchange lines

    transpose_k<<<dim3(48, 32), dim3(32, 8), 0, stream>>>(W_pre,  Wt_pre,  1024, 1536);
    transpose_k<<<dim3(48, 32), dim3(32, 8), 0, stream>>>(W_post, Wt_post, 1024, 1536);
    transpose_k<<<dim3(32, 32), dim3(32, 8), 0, stream>>>(W_ad,   Wt_ad,   1024, 1024);
    transpose_k<<<dim3(32, 8),  dim3(32, 8), 0, stream>>>(W_out,  Wt_out,  256,  1024);

    ip_gemm2<<<dim3(4, 256), 256, 0, stream>>>(inp, Wt_pre, b_pre, IP_pre,
                                               Wt_post, b_post, IP_post);

    rsnn_pc<<<256, 640, 0, stream>>>(Wt_pre, Wt_ad, Wt_post,
                                     IP_pre, IP_post, b_ad,
                                     lines, spkO, (float*)d_out);

    out_gemm<<<4096, 256, 0, stream>>>(Wt_out, b_out, spkO, (float*)d_out);
}

// Round 13
// 1048.324 us; speedup vs baseline: 1.2535x; 1.2535x over previous
//
#include <hip/hip_runtime.h>

#pragma clang fp contract(off)

typedef unsigned long long u64;
typedef unsigned int u32;

#define ALPHA  0.9f
#define RHO    0.985f
#define BETA_A 1.8f
#define TH     1.0f
#define CAP    (1 << 24)

// ---------------------------------------------------------------------------
// Generic 32x32 tiled transpose: src[R][C] -> dst[C][R]
// ---------------------------------------------------------------------------
__global__ __launch_bounds__(256) void transpose_k(const float* __restrict__ src,
                                                   float* __restrict__ dst,
                                                   int R, int C) {
    __shared__ float tile[32][33];
    const int c0 = blockIdx.x * 32;
    const int r0 = blockIdx.y * 32;
    const int tx = threadIdx.x, ty = threadIdx.y;
#pragma unroll
    for (int i = 0; i < 4; ++i)
        tile[ty + i * 8][tx] = src[(r0 + ty + i * 8) * C + c0 + tx];
    __syncthreads();
#pragma unroll
    for (int i = 0; i < 4; ++i)
        dst[(c0 + ty + i * 8) * R + r0 + tx] = tile[tx][ty + i * 8];
}

// ---------------------------------------------------------------------------
// Merged input projection: both IP_pre and IP_post from one s_in staging
// (validated rounds 10-12: identical absmax, saves a launch + 8MB re-read).
// ---------------------------------------------------------------------------
__global__ __launch_bounds__(256) void ip_gemm2(const float* __restrict__ inp,
                                                const float* __restrict__ Wt_a,
                                                const float* __restrict__ bias_a,
                                                float* __restrict__ out_a,
                                                const float* __restrict__ Wt_b,
                                                const float* __restrict__ bias_b,
                                                float* __restrict__ out_b) {
    __shared__ __align__(16) float s_in[512 * 20];
    const int tid   = threadIdx.x;
    const int chunk = blockIdx.x;
    const int rbase = blockIdx.y * 16;

    for (int idx = tid; idx < 16 * 512; idx += 256) {
        const int r = idx >> 9, k = idx & 511;
        s_in[k * 20 + r] = inp[(rbase + r) * 512 + k];
    }
    __syncthreads();

    const int n = chunk * 256 + tid;
    float acca[16], accb[16];
#pragma unroll
    for (int r = 0; r < 16; ++r) { acca[r] = 0.f; accb[r] = 0.f; }

    for (int k = 0; k < 512; ++k) {
        const float wa = Wt_a[k * 1024 + n];
        const float wb = Wt_b[k * 1024 + n];
        const float4* p = (const float4*)(s_in + k * 20);
        const float4 x0 = p[0], x1 = p[1], x2 = p[2], x3 = p[3];
        acca[0]  = fmaf(x0.x, wa, acca[0]);  accb[0]  = fmaf(x0.x, wb, accb[0]);
        acca[1]  = fmaf(x0.y, wa, acca[1]);  accb[1]  = fmaf(x0.y, wb, accb[1]);
        acca[2]  = fmaf(x0.z, wa, acca[2]);  accb[2]  = fmaf(x0.z, wb, accb[2]);
        acca[3]  = fmaf(x0.w, wa, acca[3]);  accb[3]  = fmaf(x0.w, wb, accb[3]);
        acca[4]  = fmaf(x1.x, wa, acca[4]);  accb[4]  = fmaf(x1.x, wb, accb[4]);
        acca[5]  = fmaf(x1.y, wa, acca[5]);  accb[5]  = fmaf(x1.y, wb, accb[5]);
        acca[6]  = fmaf(x1.z, wa, acca[6]);  accb[6]  = fmaf(x1.z, wb, accb[6]);
        acca[7]  = fmaf(x1.w, wa, acca[7]);  accb[7]  = fmaf(x1.w, wb, accb[7]);
        acca[8]  = fmaf(x2.x, wa, acca[8]);  accb[8]  = fmaf(x2.x, wb, accb[8]);
        acca[9]  = fmaf(x2.y, wa, acca[9]);  accb[9]  = fmaf(x2.y, wb, accb[9]);
        acca[10] = fmaf(x2.z, wa, acca[10]); accb[10] = fmaf(x2.z, wb, accb[10]);
        acca[11] = fmaf(x2.w, wa, acca[11]); accb[11] = fmaf(x2.w, wb, accb[11]);
        acca[12] = fmaf(x3.x, wa, acca[12]); accb[12] = fmaf(x3.x, wb, accb[12]);
        acca[13] = fmaf(x3.y, wa, acca[13]); accb[13] = fmaf(x3.y, wb, accb[13]);
        acca[14] = fmaf(x3.z, wa, acca[14]); accb[14] = fmaf(x3.z, wb, accb[14]);
        acca[15] = fmaf(x3.w, wa, acca[15]); accb[15] = fmaf(x3.w, wb, accb[15]);
    }
    const float bna = bias_a[n];
    const float bnb = bias_b[n];
#pragma unroll
    for (int r = 0; r < 16; ++r) {
        out_a[(rbase + r) * 1024 + n] = acca[r] + bna;
        out_b[(rbase + r) * 1024 + n] = accb[r] + bnb;
    }
}

// ---------------------------------------------------------------------------
__device__ __forceinline__ u64 ld_u64(const u64* p) {
    return __hip_atomic_load(p, __ATOMIC_RELAXED, __HIP_MEMORY_SCOPE_AGENT);
}
__device__ __forceinline__ void st_u64(u64* p, u64 v) {
    __hip_atomic_store(p, v, __ATOMIC_RELAXED, __HIP_MEMORY_SCOPE_AGENT);
}

// Gather over byte-offset list segment [i0, i1), i0 % 4 == 0.
// 4 accumulator chains (round 7's validated sweet spot: 8 chains regress 30%
// via per-CU VMEM queue back-pressure, round 12).
__device__ __forceinline__ float gatherseg(const char* __restrict__ Wb,
                                           const int* __restrict__ list,
                                           int i0, int i1, int colB) {
    float a0 = 0.f, a1 = 0.f, a2 = 0.f, a3 = 0.f;
    int i = i0;
    for (; i + 4 <= i1; i += 4) {
        const int4 j = *(const int4*)(list + i);
        a0 += *(const float*)(Wb + (u32)(j.x + colB));
        a1 += *(const float*)(Wb + (u32)(j.y + colB));
        a2 += *(const float*)(Wb + (u32)(j.z + colB));
        a3 += *(const float*)(Wb + (u32)(j.w + colB));
    }
    for (; i < i1; ++i) a0 += *(const float*)(Wb + (u32)(list[i] + colB));
    return (a0 + a1) + (a2 + a3);
}

// index-based gather for out_gemm
__device__ __forceinline__ float gather_idx(const float* __restrict__ W,
                                            const int* __restrict__ list, int cnt, int col) {
    float a0 = 0.f, a1 = 0.f, a2 = 0.f, a3 = 0.f;
    int i = 0;
    for (; i + 4 <= cnt; i += 4) {
        const int4 j = *(const int4*)(list + i);
        a0 += W[j.x * 256 + col];
        a1 += W[j.y * 256 + col];
        a2 += W[j.z * 256 + col];
        a3 += W[j.w * 256 + col];
    }
    for (; i < cnt; ++i) a0 += W[list[i] * 256 + col];
    return (a0 + a1) + (a2 + a3);
}

// ---------------------------------------------------------------------------
// Producer-consumer main kernel (round 7's validated 890 us engine, verbatim):
// 256 blocks x 640 threads.
// Waves 0-7 compute (slice s = (bid&7)>>1: cols [s*256,s*256+256), pair
// p = (bid>>3)*2+(bid&1): batches 2p,2p+1). Wave 8 polls exchange-1 (s_pre)
// and builds listP; wave 9 polls exchange-2 (s_a) and builds listS[par].
// Publish: each compute wave's lane0 stores 2 epoch-tagged words
// ((e<<32)|bits32) immediately after its ballot -- no barrier before publish.
// 2 barriers per phase (B1 releases listP, B2 releases listS).
// FILL-2 at epoch e finishes v_post of phase ph=e-1; s_post emitted when
// k(ph)=(ph-1)%3==2  <=>  e%3==1.
// ---------------------------------------------------------------------------
__global__ __launch_bounds__(640) void rsnn_pc(
    const float* __restrict__ Wt_pre,   // [1536][1024]
    const float* __restrict__ Wt_ad,    // [1024][1024]
    const float* __restrict__ Wt_post,  // [1536][1024]
    const float* __restrict__ IP_pre,   // [4096][1024]
    const float* __restrict__ IP_post,  // [4096][1024]
    const float* __restrict__ b_ad_p,   // [1024]
    u64* __restrict__ lines,            // [64 pairs][2 par][2 ty][64]
    u64* __restrict__ spkO,             // [4096][16]
    float* __restrict__ out)
{
    const int tid  = threadIdx.x;
    const int bid  = blockIdx.x;
    const int x    = bid & 7;
    const int g    = bid >> 3;
    const int s    = x >> 1;
    const int p    = g * 2 + (x & 1);
    const int wid  = tid >> 6;
    const int lane = tid & 63;

    __shared__ __align__(16) int listP[2][1024];      // [bi]
    __shared__ __align__(16) int listS[2][2][1024];   // [par][bi]
    __shared__ int cntP_ls[2], cntS_ls[2][2];

    const char* WadB    = (const char*)Wt_ad;
    const char* WpreAB  = (const char*)(Wt_pre  + 512 * 1024);
    const char* WpostAB = (const char*)(Wt_post + 512 * 1024);

    if (wid < 8) {
        // ============================ compute ============================
        const int bi   = tid >> 8;
        const int c    = tid & 255;
        const int col  = s * 256 + c;
        const int b    = 2 * p + bi;
        const int q    = wid & 3;
        const int colB = col * 4;

        float v_pre = 0.f, v_a = 0.f, ba = 0.f, v_post = 0.f, accA = 0.f;
        bool  sa = false;
        const float bad = b_ad_p[col];
        float g1 = 0.f;
        int halfPrev = 0, cntPrev = 0, parPrev = 0;

        for (int e = 1; e <= 96; ++e) {
            const int par = e & 1;
            const int t   = (e - 1) / 3;
            const float ipre = IP_pre[(t * 128 + b) * 1024 + col];
            u64* ln0 = lines + ((p * 2 + par) * 2 + 0) * 64;
            u64* ln1 = lines + ((p * 2 + par) * 2 + 1) * 64;

            // ---- A: v_pre update, immediate per-wave publish ----
            v_pre = ALPHA * v_pre + ipre + accA;
            float d = v_pre - TH;
            const bool sp = d > 0.f;
            if (sp) v_pre = d;
            {
                const u64 m = __ballot(sp);
                if (lane == 0) {
                    const u64 eh = ((u64)e) << 32;
                    st_u64(&ln0[(s * 2 + bi) * 8 + 2 * q],     eh | (m & 0xffffffffull));
                    st_u64(&ln0[(s * 2 + bi) * 8 + 2 * q + 1], eh | (m >> 32));
                }
            }
            // ---- FILL-1: first half of C(e-1) gather ----
            if (e >= 2)
                g1 = gatherseg(WpostAB, listS[parPrev][bi], 0, halfPrev, colB);
            __syncthreads();                                      // B1

            // ---- B: gather full s_pre list, v_a update, publish s_a ----
            const int cp = cntP_ls[bi];
            const float accB = gatherseg(WadB, listP[bi], 0, cp, colB);
            v_a = ALPHA * v_a + accB + bad;
            const float th = TH + BETA_A * ba;
            d = v_a - th;
            sa = d > 0.f;
            if (sa) v_a = d;
            ba = RHO * ba + (sa ? 1.f : 0.f);
            {
                const u64 m = __ballot(sa);
                if (lane == 0) {
                    const u64 eh = ((u64)e) << 32;
                    st_u64(&ln1[(s * 2 + bi) * 8 + 2 * q],     eh | (m & 0xffffffffull));
                    st_u64(&ln1[(s * 2 + bi) * 8 + 2 * q + 1], eh | (m >> 32));
                }
            }
            // ---- FILL-2: rest of C(e-1), finish v_post(e-1) ----
            if (e >= 2) {
                const float g2 = gatherseg(WpostAB, listS[parPrev][bi],
                                           halfPrev, cntPrev, colB);
                const int tp = (e - 2) / 3;
                const float ipost = IP_post[(tp * 128 + b) * 1024 + col];
                v_post = ALPHA * v_post + ipost + (g1 + g2);
                float dd = v_post - TH;
                const bool spost = dd > 0.f;
                if (spost) v_post = dd;
                if (e % 3 == 1) {   // ph=e-1 has k==2
                    const u64 m = __ballot(spost);
                    if (lane == 0)
                        st_u64(&spkO[(tp * 128 + 2 * p + bi) * 16 + s * 4 + q], m);
                }
            }
            if (e == 96)
                out[32 * 128 * 256 + b * 1024 + col] = sa ? 1.f : 0.f;
            __syncthreads();                                      // B2

            // ---- next-A gather from fresh listS ----
            const int cs = cntS_ls[par][bi];
            halfPrev = (cs >> 1) & ~3;
            cntPrev  = cs;
            parPrev  = par;
            if (e < 96)
                accA = gatherseg(WpreAB, listS[par][bi], 0, cs, colB);
        }
        // ---- epilogue: v_post(96) (par(96) == 0) ----
        {
            const float ga = gatherseg(WpostAB, listS[0][bi], 0, halfPrev, colB);
            const float gb = gatherseg(WpostAB, listS[0][bi], halfPrev, cntPrev, colB);
            const float ipost = IP_post[(31 * 128 + b) * 1024 + col];
            v_post = ALPHA * v_post + ipost + (ga + gb);
            const float dd = v_post - TH;
            const u64 m = __ballot(dd > 0.f);
            if (lane == 0)
                st_u64(&spkO[(31 * 128 + 2 * p + bi) * 16 + s * 4 + q], m);
        }
    } else if (wid == 8) {
        // ================== comm wave: exchange-1 -> listP ==================
        const int cbi = lane >> 5, r = lane & 31, sl = r >> 3, h = r & 7;
        const int jbase = (sl * 256 + h * 32) << 12;
        for (int e = 1; e <= 96; ++e) {
            const int par = e & 1;
            const u64* ln0 = lines + ((p * 2 + par) * 2 + 0) * 64;
            u64 w; int gd = 0;
            do { w = ld_u64(&ln0[(sl * 2 + cbi) * 8 + h]); }
            while ((w >> 32) != (u64)e && ++gd < CAP);
            const u32 bits = (u32)w;
            const int pc = __popc(bits);
            int incl = pc;
            for (int dlt = 1; dlt < 32; dlt <<= 1) {
                const int v = __shfl_up(incl, dlt, 32);
                if ((lane & 31) >= dlt) incl += v;
            }
            int base = incl - pc;
            u32 m = bits;
            while (m) {
                const int bt = __builtin_ctz(m);
                m &= m - 1;
                listP[cbi][base++] = jbase + (bt << 12);
            }
            if ((lane & 31) == 31) cntP_ls[cbi] = incl;
            __syncthreads();                                      // B1
            __syncthreads();                                      // B2
        }
    } else {
        // ================== comm wave: exchange-2 -> listS[par] =============
        const int cbi = lane >> 5, r = lane & 31, sl = r >> 3, h = r & 7;
        const int jbase = (sl * 256 + h * 32) << 12;
        for (int e = 1; e <= 96; ++e) {
            const int par = e & 1;
            const u64* ln1 = lines + ((p * 2 + par) * 2 + 1) * 64;
            __syncthreads();                                      // B1
            u64 w; int gd = 0;
            do { w = ld_u64(&ln1[(sl * 2 + cbi) * 8 + h]); }
            while ((w >> 32) != (u64)e && ++gd < CAP);
            const u32 bits = (u32)w;
            const int pc = __popc(bits);
            int incl = pc;
            for (int dlt = 1; dlt < 32; dlt <<= 1) {
                const int v = __shfl_up(incl, dlt, 32);
                if ((lane & 31) >= dlt) incl += v;
            }
            int base = incl - pc;
            u32 m = bits;
            while (m) {
                const int bt = __builtin_ctz(m);
                m &= m - 1;
                listS[par][cbi][base++] = jbase + (bt << 12);
            }
            if ((lane & 31) == 31) cntS_ls[par][cbi] = incl;
            __syncthreads();                                      // B2
        }
    }
}

// ---------------------------------------------------------------------------
// Final output GEMM: o[r] = s_post[r] @ W_out.T + b_out, from spkO bitmaps.
// ---------------------------------------------------------------------------
__global__ __launch_bounds__(256) void out_gemm(const float* __restrict__ Wt_out,
                                                const float* __restrict__ b_out,
                                                const u64* __restrict__ spkO,
                                                float* __restrict__ out) {
    __shared__ u64 bmp[16];
    __shared__ int pc[16];
    __shared__ __align__(16) int list[1024];
    const int r = blockIdx.x, tid = threadIdx.x;
    if (tid < 16) {
        const u64 m = ld_u64(&spkO[r * 16 + tid]);
        bmp[tid] = m;
        pc[tid]  = __popcll(m);
    }
    __syncthreads();
    int total = 0;
#pragma unroll
    for (int w = 0; w < 16; ++w) total += pc[w];
    for (int j = tid; j < 1024; j += 256) {
        const int w = j >> 6, bit = j & 63;
        const u64 m = bmp[w];
        if ((m >> bit) & 1ull) {
            int base = __popcll(m & ((1ull << bit) - 1ull));
            for (int q2 = 0; q2 < w; ++q2) base += pc[q2];
            list[base] = j;
        }
    }
    __syncthreads();
    const float acc = gather_idx(Wt_out, list, total, tid);
    out[r * 256 + tid] = acc + b_out[tid];
}

// ---------------------------------------------------------------------------
extern "C" void kernel_launch(void* const* d_in, const int* in_sizes, int n_in,
                              void* d_out, int out_size, void* d_ws, size_t ws_size,
                              hipStream_t stream) {
    (void)in_sizes; (void)n_in; (void)out_size; (void)ws_size;
    const float* inp    = (const float*)d_in[0];
    const float* W_pre  = (const float*)d_in[1];
    const float* b_pre  = (const float*)d_in[2];
    const float* W_ad   = (const float*)d_in[3];
    const float* b_ad   = (const float*)d_in[4];
    const float* W_post = (const float*)d_in[5];
    const float* b_post = (const float*)d_in[6];
    const float* W_out  = (const float*)d_in[7];
    const float* b_out  = (const float*)d_in[8];

    char* base = (char*)d_ws;
    u64*  lines = (u64*)(base + 4096);               // 128 KB exchange lines
    u64*  spkO  = (u64*)(base + 147456);             // 512 KB
    float* ws      = (float*)(base + 1048576);
    float* Wt_pre  = ws;
    float* Wt_post = Wt_pre  + 1536 * 1024;
    float* Wt_ad   = Wt_post + 1536 * 1024;
    float* Wt_out  = Wt_ad   + 1024 * 1024;
    float* IP_pre  = Wt_out  + 1024 * 256;
    float* IP_post = IP_pre  + 4096 * 1024;

    hipMemsetAsync(base, 0, 4096 + 131072, stream);  // zero exchange lines

    transpose_k<<<dim3(48, 32), dim3(32, 8), 0, stream>>>(W_pre,  Wt_pre,  1024, 1536);
    transpose_k<<<dim3(48, 32), dim3(32, 8), 0, stream>>>(W_post, Wt_post, 1024, 1536);
    transpose_k<<<dim3(32, 32), dim3(32, 8), 0, stream>>>(W_ad,   Wt_ad,   1024, 1024);
    transpose_k<<<dim3(32, 8),  dim3(32, 8), 0, stream>>>(W_out,  Wt_out,  256,  1024);

    ip_gemm2<<<dim3(4, 256), 256, 0, stream>>>(inp, Wt_pre, b_pre, IP_pre,
                                               Wt_post, b_post, IP_post);

    rsnn_pc<<<256, 640, 0, stream>>>(Wt_pre, Wt_ad, Wt_post,
                                     IP_pre, IP_post, b_ad,
                                     lines, spkO, (float*)d_out);

    out_gemm<<<4096, 256, 0, stream>>>(Wt_out, b_out, spkO, (float*)d_out);
}